// Round 3
// baseline (1758.875 us; speedup 1.0000x reference)
//
#include <hip/hip_runtime.h>

// Problem constants
#define BATCH 256
#define TT 1024
#define IN_DIM 96
#define NU 256
#define NC 10
#define EPS 0.01f
#define BETA 0.5f
#define GAMMA 0.0f

typedef _Float16 f16x8 __attribute__((ext_vector_type(8)));
typedef float f32x4 __attribute__((ext_vector_type(4)));

// workspace layout (bytes)
#define ZP_BYTES ((size_t)TT * BATCH * NU * 2)          // 134,217,728  z f16 [t][b][n]
#define WSW_OFF  ZP_BYTES
#define WSW_BYTES ((size_t)4 * 2 * 8 * 4 * 64 * 8 * 2)  // 262,144
#define ESW_OFF  (WSW_OFF + WSW_BYTES)

// ---------------------------------------------------------------------------
// prep_w: B-operand frags for Wd = 16*EPS*Dm and Wa = 16*A  (K=256, N=256 each)
// B-frag (16x16x32): lane l holds B[k=(l>>4)*8+j][n=l&15].
// Flat: [w 4][mat 2][c 8][i 4][lane 64][8 halfs]
__global__ void prep_w(const float* __restrict__ C, const float* __restrict__ B,
                       _Float16* __restrict__ Wsw) {
    int u = blockIdx.x * 256 + threadIdx.x;   // 16384 units
    int l = u & 63;
    int i = (u >> 6) & 3;
    int c = (u >> 8) & 7;
    int mat = (u >> 11) & 1;
    int w = u >> 12;
    int n = w * 64 + i * 16 + (l & 15);
    int kb = c * 32 + (l >> 4) * 8;
    const float* M = mat ? C : B;             // mat0: Dm from B; mat1: A from C
    float scale = mat ? 16.0f : (16.0f * EPS);
    f16x8 v;
#pragma unroll
    for (int j = 0; j < 8; j++) {
        int k = kb + j;
        float m1 = M[k * NU + n];
        float m2 = M[n * NU + k];
        float val = BETA * (m1 - m2) + (1.0f - BETA) * (m1 + m2)
                    - ((k == n) ? GAMMA : 0.0f);
        v[j] = (_Float16)(val * scale);
    }
    ((f16x8*)Wsw)[u] = v;
}

// ---------------------------------------------------------------------------
// prep_e: E_w [256][96] -> B-frags for z = x @ E_w^T (K=96, N=256), unscaled.
// Flat: [w 4][c 3][i 4][lane 64][8 halfs]
__global__ void prep_e(const float* __restrict__ Ew, _Float16* __restrict__ Esw) {
    int u = blockIdx.x * 256 + threadIdx.x;   // 3072 units
    int l = u & 63;
    int i = (u >> 6) & 3;
    int wc = u >> 8;
    int c = wc % 3;
    int w = wc / 3;
    int n = w * 64 + i * 16 + (l & 15);
    int kb = c * 32 + (l >> 4) * 8;
    f16x8 v;
#pragma unroll
    for (int j = 0; j < 8; j++)
        v[j] = (_Float16)Ew[n * IN_DIM + kb + j];
    ((f16x8*)Esw)[u] = v;
}

// ---------------------------------------------------------------------------
// zproj (round-1 proven version): z[t][b][n] = f16(x[b][t][:] @ E_w^T + E_b)
// Block = 256 thr (4 waves), handles 64 bt-rows; wave w owns cols w*64..+63.
__global__ __launch_bounds__(256) void zproj(const float* __restrict__ x,
                                             const float* __restrict__ Eb,
                                             const _Float16* __restrict__ Esw,
                                             _Float16* __restrict__ zp) {
    __shared__ __align__(16) _Float16 xh[64 * 104];  // x rows as f16, pad 96->104
    __shared__ float eb[NU];
    int tid = threadIdx.x;
    int l = tid & 63, w = tid >> 6, m = l & 15, quad = l >> 4;
    size_t R0 = (size_t)blockIdx.x * 64;

    const float* xb = x + R0 * IN_DIM;
#pragma unroll
    for (int it = 0; it < 24; it++) {         // 64*96/256 = 24 per thread
        int idx = tid + it * 256;
        int r = idx / 96, k = idx - r * 96;
        xh[r * 104 + k] = (_Float16)xb[idx];
    }
    eb[tid] = Eb[tid];

    f16x8 ef[3][4];
    const f16x8* Ep = (const f16x8*)Esw;
#pragma unroll
    for (int c = 0; c < 3; c++)
#pragma unroll
        for (int i = 0; i < 4; i++)
            ef[c][i] = Ep[((w * 3 + c) * 4 + i) * 64 + l];
    __syncthreads();

    f32x4 zero4 = {0.f, 0.f, 0.f, 0.f};
    f32x4 acc[4][4];
#pragma unroll
    for (int mt = 0; mt < 4; mt++)
#pragma unroll
        for (int i = 0; i < 4; i++) acc[mt][i] = zero4;

#pragma unroll
    for (int mt = 0; mt < 4; mt++) {
#pragma unroll
        for (int c = 0; c < 3; c++) {
            f16x8 af = *(const f16x8*)&xh[(mt * 16 + m) * 104 + c * 32 + quad * 8];
#pragma unroll
            for (int i = 0; i < 4; i++)
                acc[mt][i] = __builtin_amdgcn_mfma_f32_16x16x32_f16(af, ef[c][i],
                                                                    acc[mt][i], 0, 0, 0);
        }
    }

#pragma unroll
    for (int mt = 0; mt < 4; mt++)
#pragma unroll
        for (int i = 0; i < 4; i++) {
            int col = w * 64 + i * 16 + m;
            float ebv = eb[col];
#pragma unroll
            for (int r = 0; r < 4; r++) {
                size_t gr = R0 + (size_t)(mt * 16 + quad * 4 + r);
                size_t b = gr >> 10, t = gr & 1023;
                zp[(t * BATCH + b) * NU + col] = (_Float16)(acc[mt][i][r] + ebv);
            }
        }
}

// ---------------------------------------------------------------------------
// Recurrence: 16 WGs x 256 thr (4 waves). WG owns 16 batch rows. Wave w owns
// cols w*64..+63 of BOTH Dm and A (256 VGPRs of resident weights), so the
// MFMA C-layout matches the update layout: master h (fp32) and tanh update
// stay in registers; only new-h (f16, /16) crosses LDS. One barrier/step.
// z: canonical [t][b][n], 16 scalar f16 loads per step, chunk-4 prefetched.

__device__ __forceinline__ void load_zchunk(_Float16 zb[4][16],
                                            const _Float16* __restrict__ zp,
                                            int tb, int zrow, int colb) {
#pragma unroll
    for (int s = 0; s < 4; s++) {
        int ts = tb + s; ts = (ts > TT - 1) ? TT - 1 : ts;
#pragma unroll
        for (int r = 0; r < 4; r++)
#pragma unroll
            for (int i = 0; i < 4; i++)
                zb[s][i * 4 + r] = zp[((size_t)ts * 256 + zrow + r) * 256 + colb + i * 16];
    }
}

__device__ __forceinline__ void step_fn(const _Float16* __restrict__ hb,
                                        _Float16* __restrict__ hn,
                                        const f16x8 wd[8][4], const f16x8 wa[8][4],
                                        float hm[16], const _Float16 zs[16],
                                        int m, int q, int w) {
    f32x4 faccD[4], faccA[4];
    f32x4 zero4 = {0.f, 0.f, 0.f, 0.f};
#pragma unroll
    for (int i = 0; i < 4; i++) {
        faccD[i] = zero4;
        f32x4 zi = {(float)zs[i * 4 + 0], (float)zs[i * 4 + 1],
                    (float)zs[i * 4 + 2], (float)zs[i * 4 + 3]};
        faccA[i] = zi;                         // fold z into A-part acc init
    }

#pragma unroll
    for (int c = 0; c < 8; c++) {
        f16x8 af = *(const f16x8*)&hb[m * 264 + c * 32 + q * 8];
#pragma unroll
        for (int i = 0; i < 4; i++) {
            faccD[i] = __builtin_amdgcn_mfma_f32_16x16x32_f16(af, wd[c][i], faccD[i], 0, 0, 0);
            faccA[i] = __builtin_amdgcn_mfma_f32_16x16x32_f16(af, wa[c][i], faccA[i], 0, 0, 0);
        }
    }

#pragma unroll
    for (int i = 0; i < 4; i++) {
        int n = w * 64 + i * 16 + m;
#pragma unroll
        for (int r = 0; r < 4; r++) {
            int row = q * 4 + r;
            float xin = faccA[i][r];           // h@A + z
            float e = __expf(2.0f * xin);
            float th = 1.0f - 2.0f / (e + 1.0f);
            hm[i * 4 + r] += faccD[i][r] + EPS * th;  // faccD = EPS*(h@Dm)
            hn[row * 264 + n] = (_Float16)(hm[i * 4 + r] * 0.0625f);
        }
    }
    __syncthreads();
}

__global__ __launch_bounds__(256, 1) void recur(const _Float16* __restrict__ Wsw,
                                                const _Float16* __restrict__ zp,
                                                const float* __restrict__ Dw,
                                                const float* __restrict__ Db,
                                                float* __restrict__ out) {
    __shared__ __align__(16) _Float16 hbuf0[16 * 264];
    __shared__ __align__(16) _Float16 hbuf1[16 * 264];
    __shared__ float Yep[16 * 257];
    int tid = threadIdx.x;
    int l = tid & 63, w = tid >> 6, m = l & 15, q = l >> 4;
    int wg = blockIdx.x;

    // resident weight fragments: 64 f16x8 = 256 VGPRs
    f16x8 wd[8][4], wa[8][4];
    const f16x8* Wp = (const f16x8*)Wsw;
#pragma unroll
    for (int c = 0; c < 8; c++)
#pragma unroll
        for (int i = 0; i < 4; i++) {
            wd[c][i] = Wp[(((w * 2 + 0) * 8 + c) * 4 + i) * 64 + l];
            wa[c][i] = Wp[(((w * 2 + 1) * 8 + c) * 4 + i) * 64 + l];
        }

    float hm[16];
#pragma unroll
    for (int e = 0; e < 16; e++) hm[e] = 0.0f;
    for (int idx = tid; idx < 16 * 264; idx += 256) hbuf0[idx] = (_Float16)0.0f;

    int zrow = wg * 16 + q * 4;               // this thread's h-row base
    int colb = w * 64 + m;                    // this thread's h-col base
    _Float16 zA[4][16], zB[4][16];
    load_zchunk(zA, zp, 0, zrow, colb);
    load_zchunk(zB, zp, 4, zrow, colb);
    __syncthreads();

    for (int t = 0; t < TT; t += 8) {
        step_fn(hbuf0, hbuf1, wd, wa, hm, zA[0], m, q, w);
        step_fn(hbuf1, hbuf0, wd, wa, hm, zA[1], m, q, w);
        step_fn(hbuf0, hbuf1, wd, wa, hm, zA[2], m, q, w);
        step_fn(hbuf1, hbuf0, wd, wa, hm, zA[3], m, q, w);
        load_zchunk(zA, zp, t + 8, zrow, colb);    // drains at next step's barrier
        step_fn(hbuf0, hbuf1, wd, wa, hm, zB[0], m, q, w);
        step_fn(hbuf1, hbuf0, wd, wa, hm, zB[1], m, q, w);
        step_fn(hbuf0, hbuf1, wd, wa, hm, zB[2], m, q, w);
        step_fn(hbuf1, hbuf0, wd, wa, hm, zB[3], m, q, w);
        load_zchunk(zB, zp, t + 12, zrow, colb);
    }

    // epilogue: out[b][c] = h[b][:] @ Dw[c][:] + Db[c]
#pragma unroll
    for (int i = 0; i < 4; i++)
#pragma unroll
        for (int r = 0; r < 4; r++)
            Yep[(q * 4 + r) * 257 + w * 64 + i * 16 + m] = hm[i * 4 + r];
    __syncthreads();
    if (tid < 160) {
        int rr = tid / 10, c = tid - rr * 10;
        float s = Db[c];
        for (int k = 0; k < 256; k++) s += Yep[rr * 257 + k] * Dw[c * 256 + k];
        out[(wg * 16 + rr) * 10 + c] = s;
    }
}

// ---------------------------------------------------------------------------
extern "C" void kernel_launch(void* const* d_in, const int* in_sizes, int n_in,
                              void* d_out, int out_size, void* d_ws, size_t ws_size,
                              hipStream_t stream) {
    const float* x  = (const float*)d_in[0];
    const float* Ew = (const float*)d_in[1];
    const float* Eb = (const float*)d_in[2];
    const float* C  = (const float*)d_in[3];
    const float* B  = (const float*)d_in[4];
    const float* Dw = (const float*)d_in[5];
    const float* Db = (const float*)d_in[6];
    float* out = (float*)d_out;

    char* ws = (char*)d_ws;
    _Float16* zp  = (_Float16*)(ws);
    _Float16* Wsw = (_Float16*)(ws + WSW_OFF);
    _Float16* Esw = (_Float16*)(ws + ESW_OFF);

    hipLaunchKernelGGL(prep_w, dim3(64), dim3(256), 0, stream, C, B, Wsw);
    hipLaunchKernelGGL(prep_e, dim3(12), dim3(256), 0, stream, Ew, Esw);
    hipLaunchKernelGGL(zproj, dim3(4096), dim3(256), 0, stream, x, Eb, Esw, zp);
    hipLaunchKernelGGL(recur, dim3(16), dim3(256), 0, stream, Wsw, zp, Dw, Db, out);
}

// Round 5
// 1401.769 us; speedup vs baseline: 1.2548x; 1.2548x over previous
//
#include <hip/hip_runtime.h>

// Problem constants
#define BATCH 256
#define TT 1024
#define IN_DIM 96
#define NU 256
#define NC 10
#define EPS 0.01f
#define BETA 0.5f
#define GAMMA 0.0f

typedef _Float16 f16x8 __attribute__((ext_vector_type(8)));
typedef float f32x4 __attribute__((ext_vector_type(4)));

// workspace layout (bytes)
#define ZP_BYTES ((size_t)TT * BATCH * NU * 2)          // 134,217,728  z f16 [t][b][n]
#define WSW_OFF  ZP_BYTES
#define WSW_BYTES ((size_t)16384 * 16)                  // 262,144
#define ESW_OFF  (WSW_OFF + WSW_BYTES)

// ---------------------------------------------------------------------------
// prep_w: B-operand frags for Wd = 16*EPS*Dm and Wa = 16*A  (K=256 each).
// recur wave w (0..7) owns N-cols [w*32, w*32+32) of BOTH matrices.
// B-frag (16x16x32): lane l holds W[k=(l>>4)*8+j][n = tile_col + (l&15)].
// Flat: [w 8][mat 2][c 8][i 2][lane 64][8 halfs]
__global__ void prep_w(const float* __restrict__ C, const float* __restrict__ B,
                       _Float16* __restrict__ Wsw) {
    int u = blockIdx.x * 256 + threadIdx.x;   // 16384 units
    int l = u & 63;
    int i = (u >> 6) & 1;
    int c = (u >> 7) & 7;
    int mat = (u >> 10) & 1;
    int w = u >> 11;                          // 0..7
    int n = w * 32 + i * 16 + (l & 15);
    int kb = c * 32 + (l >> 4) * 8;
    const float* M = mat ? C : B;             // mat0: Dm from B; mat1: A from C
    float scale = mat ? 16.0f : (16.0f * EPS);
    f16x8 v;
#pragma unroll
    for (int j = 0; j < 8; j++) {
        int k = kb + j;
        float m1 = M[k * NU + n];
        float m2 = M[n * NU + k];
        float val = BETA * (m1 - m2) + (1.0f - BETA) * (m1 + m2)
                    - ((k == n) ? GAMMA : 0.0f);
        v[j] = (_Float16)(val * scale);
    }
    ((f16x8*)Wsw)[u] = v;
}

// ---------------------------------------------------------------------------
// prep_e: E_w [256][96] -> B-frags for z = x @ E_w^T (K=96, N=256), unscaled.
// Flat: [w 4][c 3][i 4][lane 64][8 halfs]
__global__ void prep_e(const float* __restrict__ Ew, _Float16* __restrict__ Esw) {
    int u = blockIdx.x * 256 + threadIdx.x;   // 3072 units
    int l = u & 63;
    int i = (u >> 6) & 3;
    int wc = u >> 8;
    int c = wc % 3;
    int w = wc / 3;
    int n = w * 64 + i * 16 + (l & 15);
    int kb = c * 32 + (l >> 4) * 8;
    f16x8 v;
#pragma unroll
    for (int j = 0; j < 8; j++)
        v[j] = (_Float16)Ew[n * IN_DIM + kb + j];
    ((f16x8*)Esw)[u] = v;
}

// ---------------------------------------------------------------------------
// zproj (round-1/3 proven version): z[t][b][n] = f16(x[b][t][:] @ E_w^T + E_b)
__global__ __launch_bounds__(256) void zproj(const float* __restrict__ x,
                                             const float* __restrict__ Eb,
                                             const _Float16* __restrict__ Esw,
                                             _Float16* __restrict__ zp) {
    __shared__ __align__(16) _Float16 xh[64 * 104];  // x rows as f16, pad 96->104
    __shared__ float eb[NU];
    int tid = threadIdx.x;
    int l = tid & 63, w = tid >> 6, m = l & 15, quad = l >> 4;
    size_t R0 = (size_t)blockIdx.x * 64;

    const float* xb = x + R0 * IN_DIM;
#pragma unroll
    for (int it = 0; it < 24; it++) {         // 64*96/256 = 24 per thread
        int idx = tid + it * 256;
        int r = idx / 96, k = idx - r * 96;
        xh[r * 104 + k] = (_Float16)xb[idx];
    }
    eb[tid] = Eb[tid];

    f16x8 ef[3][4];
    const f16x8* Ep = (const f16x8*)Esw;
#pragma unroll
    for (int c = 0; c < 3; c++)
#pragma unroll
        for (int i = 0; i < 4; i++)
            ef[c][i] = Ep[((w * 3 + c) * 4 + i) * 64 + l];
    __syncthreads();

    f32x4 zero4 = {0.f, 0.f, 0.f, 0.f};
    f32x4 acc[4][4];
#pragma unroll
    for (int mt = 0; mt < 4; mt++)
#pragma unroll
        for (int i = 0; i < 4; i++) acc[mt][i] = zero4;

#pragma unroll
    for (int mt = 0; mt < 4; mt++) {
#pragma unroll
        for (int c = 0; c < 3; c++) {
            f16x8 af = *(const f16x8*)&xh[(mt * 16 + m) * 104 + c * 32 + quad * 8];
#pragma unroll
            for (int i = 0; i < 4; i++)
                acc[mt][i] = __builtin_amdgcn_mfma_f32_16x16x32_f16(af, ef[c][i],
                                                                    acc[mt][i], 0, 0, 0);
        }
    }

#pragma unroll
    for (int mt = 0; mt < 4; mt++)
#pragma unroll
        for (int i = 0; i < 4; i++) {
            int col = w * 64 + i * 16 + m;
            float ebv = eb[col];
#pragma unroll
            for (int r = 0; r < 4; r++) {
                size_t gr = R0 + (size_t)(mt * 16 + quad * 4 + r);
                size_t b = gr >> 10, t = gr & 1023;
                zp[(t * BATCH + b) * NU + col] = (_Float16)(acc[mt][i][r] + ebv);
            }
        }
}

// ---------------------------------------------------------------------------
// Recurrence v5: 16 WGs x 512 thr (8 waves, 2/SIMD). Wave w owns cols
// [w*32, w*32+32) of BOTH Dm and A = 128 weight VGPRs, asm-pinned resident
// (rounds 1/3 showed the compiler otherwise re-loads them every step ->
// L2-BW-bound). SIMD-partner waves overlap MFMA and update VALU (m114).
// One __syncthreads per step. z: canonical [t][b][n], 8 scalar f16 loads
// per step, chunk-2 prefetched (proven round-3 pattern).

__device__ __forceinline__ void load_zchunk(_Float16 zb[2][8],
                                            const _Float16* __restrict__ zp,
                                            int tb, int zrow, int colb) {
#pragma unroll
    for (int s = 0; s < 2; s++) {
        int ts = tb + s; ts = (ts > TT - 1) ? TT - 1 : ts;
#pragma unroll
        for (int r = 0; r < 4; r++)
#pragma unroll
            for (int i = 0; i < 2; i++)
                zb[s][i * 4 + r] = zp[((size_t)ts * 256 + zrow + r) * 256 + colb + i * 16];
    }
}

__device__ __forceinline__ void step_fn(const _Float16* __restrict__ hb,
                                        _Float16* __restrict__ hn,
                                        const f16x8 wd[8][2], const f16x8 wa[8][2],
                                        float hm[8], const _Float16 zs[8],
                                        int m, int q, int w) {
    f32x4 faccD[2], faccA[2];
    f32x4 zero4 = {0.f, 0.f, 0.f, 0.f};
#pragma unroll
    for (int i = 0; i < 2; i++) {
        faccD[i] = zero4;
        f32x4 zi = {(float)zs[i * 4 + 0], (float)zs[i * 4 + 1],
                    (float)zs[i * 4 + 2], (float)zs[i * 4 + 3]};
        faccA[i] = zi;                         // fold z into A-part acc init
    }

#pragma unroll
    for (int c = 0; c < 8; c++) {
        f16x8 af = *(const f16x8*)&hb[m * 264 + c * 32 + q * 8];
#pragma unroll
        for (int i = 0; i < 2; i++) {
            faccD[i] = __builtin_amdgcn_mfma_f32_16x16x32_f16(af, wd[c][i], faccD[i], 0, 0, 0);
            faccA[i] = __builtin_amdgcn_mfma_f32_16x16x32_f16(af, wa[c][i], faccA[i], 0, 0, 0);
        }
    }

#pragma unroll
    for (int i = 0; i < 2; i++) {
        int n = w * 32 + i * 16 + m;
#pragma unroll
        for (int r = 0; r < 4; r++) {
            int row = q * 4 + r;
            float xin = faccA[i][r];           // h@A + z
            float e = __expf(2.0f * xin);
            float th = 1.0f - 2.0f / (e + 1.0f);
            hm[i * 4 + r] += faccD[i][r] + EPS * th;  // faccD = EPS*(h@Dm)
            hn[row * 264 + n] = (_Float16)(hm[i * 4 + r] * 0.0625f);
        }
    }
    __syncthreads();
}

__global__ __launch_bounds__(512, 2) void recur(const _Float16* __restrict__ Wsw,
                                                const _Float16* __restrict__ zp,
                                                const float* __restrict__ Dw,
                                                const float* __restrict__ Db,
                                                float* __restrict__ out) {
    __shared__ __align__(16) _Float16 hbuf0[16 * 264];
    __shared__ __align__(16) _Float16 hbuf1[16 * 264];
    __shared__ float Yep[16 * 257];
    int tid = threadIdx.x;
    int l = tid & 63, w = tid >> 6, m = l & 15, q = l >> 4;
    int wg = blockIdx.x;

    // resident weight fragments: 32 f16x8 = 128 VGPRs
    f16x8 wd[8][2], wa[8][2];
    const f16x8* Wp = (const f16x8*)Wsw;
#pragma unroll
    for (int c = 0; c < 8; c++)
#pragma unroll
        for (int i = 0; i < 2; i++) {
            wd[c][i] = Wp[(((w * 2 + 0) * 8 + c) * 2 + i) * 64 + l];
            wa[c][i] = Wp[(((w * 2 + 1) * 8 + c) * 2 + i) * 64 + l];
        }
    // Pin: make values opaque so the compiler cannot rematerialize the
    // global loads inside the step loop (rounds 1/3: VGPR_Count < footprint
    // proved it re-loads weights every step -> L2-bound at ~1.5 ms).
#pragma unroll
    for (int c = 0; c < 8; c++)
#pragma unroll
        for (int i = 0; i < 2; i++)
            asm volatile("" : "+v"(wd[c][i]), "+v"(wa[c][i]));

    float hm[8];
#pragma unroll
    for (int e = 0; e < 8; e++) hm[e] = 0.0f;
    for (int idx = tid; idx < 16 * 264; idx += 512) hbuf0[idx] = (_Float16)0.0f;

    int zrow = wg * 16 + q * 4;               // this thread's h-row base
    int colb = w * 32 + m;                    // this thread's h-col base
    _Float16 zA[2][8], zB[2][8];
    load_zchunk(zA, zp, 0, zrow, colb);
    load_zchunk(zB, zp, 2, zrow, colb);
    __syncthreads();

    for (int t = 0; t < TT; t += 4) {
        step_fn(hbuf0, hbuf1, wd, wa, hm, zA[0], m, q, w);
        step_fn(hbuf1, hbuf0, wd, wa, hm, zA[1], m, q, w);
        load_zchunk(zA, zp, t + 4, zrow, colb);   // drains at next step barrier
        step_fn(hbuf0, hbuf1, wd, wa, hm, zB[0], m, q, w);
        step_fn(hbuf1, hbuf0, wd, wa, hm, zB[1], m, q, w);
        load_zchunk(zB, zp, t + 6, zrow, colb);
    }

    // epilogue: out[b][c] = h[b][:] @ Dw[c][:] + Db[c]
#pragma unroll
    for (int i = 0; i < 2; i++)
#pragma unroll
        for (int r = 0; r < 4; r++)
            Yep[(q * 4 + r) * 257 + w * 32 + i * 16 + m] = hm[i * 4 + r];
    __syncthreads();
    if (tid < 160) {
        int rr = tid / 10, c = tid - rr * 10;
        float s = Db[c];
        for (int k = 0; k < 256; k++) s += Yep[rr * 257 + k] * Dw[c * 256 + k];
        out[(wg * 16 + rr) * 10 + c] = s;
    }
}

// ---------------------------------------------------------------------------
extern "C" void kernel_launch(void* const* d_in, const int* in_sizes, int n_in,
                              void* d_out, int out_size, void* d_ws, size_t ws_size,
                              hipStream_t stream) {
    const float* x  = (const float*)d_in[0];
    const float* Ew = (const float*)d_in[1];
    const float* Eb = (const float*)d_in[2];
    const float* C  = (const float*)d_in[3];
    const float* B  = (const float*)d_in[4];
    const float* Dw = (const float*)d_in[5];
    const float* Db = (const float*)d_in[6];
    float* out = (float*)d_out;

    char* ws = (char*)d_ws;
    _Float16* zp  = (_Float16*)(ws);
    _Float16* Wsw = (_Float16*)(ws + WSW_OFF);
    _Float16* Esw = (_Float16*)(ws + ESW_OFF);

    hipLaunchKernelGGL(prep_w, dim3(64), dim3(256), 0, stream, C, B, Wsw);
    hipLaunchKernelGGL(prep_e, dim3(12), dim3(256), 0, stream, Ew, Esw);
    hipLaunchKernelGGL(zproj, dim3(4096), dim3(256), 0, stream, x, Eb, Esw, zp);
    hipLaunchKernelGGL(recur, dim3(16), dim3(512), 0, stream, Wsw, zp, Dw, Db, out);
}

// Round 6
// 1083.118 us; speedup vs baseline: 1.6239x; 1.2942x over previous
//
#include <hip/hip_runtime.h>

// Problem constants
#define BATCH 256
#define TT 1024
#define IN_DIM 96
#define NU 256
#define NC 10
#define EPS 0.01f
#define BETA 0.5f
#define GAMMA 0.0f

typedef _Float16 f16x8 __attribute__((ext_vector_type(8)));
typedef float f32x4 __attribute__((ext_vector_type(4)));

// workspace layout (bytes)
#define ZP_BYTES ((size_t)TT * BATCH * NU * 2)          // 134,217,728  z f16 [t][b][n]
#define WSW_OFF  ZP_BYTES
#define WSW_BYTES ((size_t)16384 * 16)                  // 262,144
#define ESW_OFF  (WSW_OFF + WSW_BYTES)

// ---------------------------------------------------------------------------
// prep_w: B-operand frags. Stored h' = h/16 (f16). To make
//   faccD = h' @ Wd = (EPS/16)*(h@Dm)  -> Wd = EPS*Dm
//   faccA = h' @ Wa = h@A              -> Wa = 16*A
// recur wave w (0..7) owns N-cols [w*32, w*32+32) of BOTH matrices.
// B-frag (16x16x32): lane l holds W[k=(l>>4)*8+j][n = tile_col + (l&15)].
// Flat: [w 8][mat 2][c 8][i 2][lane 64][8 halfs]
__global__ void prep_w(const float* __restrict__ C, const float* __restrict__ B,
                       _Float16* __restrict__ Wsw) {
    int u = blockIdx.x * 256 + threadIdx.x;   // 16384 units
    int l = u & 63;
    int i = (u >> 6) & 1;
    int c = (u >> 7) & 7;
    int mat = (u >> 10) & 1;
    int w = u >> 11;                          // 0..7
    int n = w * 32 + i * 16 + (l & 15);
    int kb = c * 32 + (l >> 4) * 8;
    const float* M = mat ? C : B;             // mat0: Dm from B; mat1: A from C
    float scale = mat ? 16.0f : EPS;
    f16x8 v;
#pragma unroll
    for (int j = 0; j < 8; j++) {
        int k = kb + j;
        float m1 = M[k * NU + n];
        float m2 = M[n * NU + k];
        float val = BETA * (m1 - m2) + (1.0f - BETA) * (m1 + m2)
                    - ((k == n) ? GAMMA : 0.0f);
        v[j] = (_Float16)(val * scale);
    }
    ((f16x8*)Wsw)[u] = v;
}

// ---------------------------------------------------------------------------
// prep_e: E_w [256][96] -> B-frags for z = x @ E_w^T (K=96, N=256), unscaled.
// Flat: [w 4][c 3][i 4][lane 64][8 halfs]
__global__ void prep_e(const float* __restrict__ Ew, _Float16* __restrict__ Esw) {
    int u = blockIdx.x * 256 + threadIdx.x;   // 3072 units
    int l = u & 63;
    int i = (u >> 6) & 3;
    int wc = u >> 8;
    int c = wc % 3;
    int w = wc / 3;
    int n = w * 64 + i * 16 + (l & 15);
    int kb = c * 32 + (l >> 4) * 8;
    f16x8 v;
#pragma unroll
    for (int j = 0; j < 8; j++)
        v[j] = (_Float16)Ew[n * IN_DIM + kb + j];
    ((f16x8*)Esw)[u] = v;
}

// ---------------------------------------------------------------------------
// zproj (proven): z[t][b][n] = f16(x[b][t][:] @ E_w^T + E_b)
__global__ __launch_bounds__(256) void zproj(const float* __restrict__ x,
                                             const float* __restrict__ Eb,
                                             const _Float16* __restrict__ Esw,
                                             _Float16* __restrict__ zp) {
    __shared__ __align__(16) _Float16 xh[64 * 104];  // x rows as f16, pad 96->104
    __shared__ float eb[NU];
    int tid = threadIdx.x;
    int l = tid & 63, w = tid >> 6, m = l & 15, quad = l >> 4;
    size_t R0 = (size_t)blockIdx.x * 64;

    const float* xb = x + R0 * IN_DIM;
#pragma unroll
    for (int it = 0; it < 24; it++) {         // 64*96/256 = 24 per thread
        int idx = tid + it * 256;
        int r = idx / 96, k = idx - r * 96;
        xh[r * 104 + k] = (_Float16)xb[idx];
    }
    eb[tid] = Eb[tid];

    f16x8 ef[3][4];
    const f16x8* Ep = (const f16x8*)Esw;
#pragma unroll
    for (int c = 0; c < 3; c++)
#pragma unroll
        for (int i = 0; i < 4; i++)
            ef[c][i] = Ep[((w * 3 + c) * 4 + i) * 64 + l];
    __syncthreads();

    f32x4 zero4 = {0.f, 0.f, 0.f, 0.f};
    f32x4 acc[4][4];
#pragma unroll
    for (int mt = 0; mt < 4; mt++)
#pragma unroll
        for (int i = 0; i < 4; i++) acc[mt][i] = zero4;

#pragma unroll
    for (int mt = 0; mt < 4; mt++) {
#pragma unroll
        for (int c = 0; c < 3; c++) {
            f16x8 af = *(const f16x8*)&xh[(mt * 16 + m) * 104 + c * 32 + quad * 8];
#pragma unroll
            for (int i = 0; i < 4; i++)
                acc[mt][i] = __builtin_amdgcn_mfma_f32_16x16x32_f16(af, ef[c][i],
                                                                    acc[mt][i], 0, 0, 0);
        }
    }

#pragma unroll
    for (int mt = 0; mt < 4; mt++)
#pragma unroll
        for (int i = 0; i < 4; i++) {
            int col = w * 64 + i * 16 + m;
            float ebv = eb[col];
#pragma unroll
            for (int r = 0; r < 4; r++) {
                size_t gr = R0 + (size_t)(mt * 16 + quad * 4 + r);
                size_t b = gr >> 10, t = gr & 1023;
                zp[(t * BATCH + b) * NU + col] = (_Float16)(acc[mt][i][r] + ebv);
            }
        }
}

// ---------------------------------------------------------------------------
// Recurrence v6: structure identical to green round-5 (16 WGs x 8 waves,
// AGPR-resident weights, one __syncthreads/step, z chunk-2 prefetch).
// Changes: fast tanh (raw exp2+rcp builtins, no full-precision divide),
// pre-scaled master hm' = h/16 (direct f16 cast store, no rescale muls).

__device__ __forceinline__ void load_zchunk(_Float16 zb[2][8],
                                            const _Float16* __restrict__ zp,
                                            int tb, int zrow, int colb) {
#pragma unroll
    for (int s = 0; s < 2; s++) {
        int ts = tb + s; ts = (ts > TT - 1) ? TT - 1 : ts;
#pragma unroll
        for (int r = 0; r < 4; r++)
#pragma unroll
            for (int i = 0; i < 2; i++)
                zb[s][i * 4 + r] = zp[((size_t)ts * 256 + zrow + r) * 256 + colb + i * 16];
    }
}

__device__ __forceinline__ void step_fn(const _Float16* __restrict__ hb,
                                        _Float16* __restrict__ hn,
                                        const f16x8 wd[8][2], const f16x8 wa[8][2],
                                        float hm[8], const _Float16 zs[8],
                                        int m, int q, int w) {
    f32x4 faccD[2], faccA[2];
    f32x4 zero4 = {0.f, 0.f, 0.f, 0.f};
#pragma unroll
    for (int i = 0; i < 2; i++) {
        faccD[i] = zero4;
        f32x4 zi = {(float)zs[i * 4 + 0], (float)zs[i * 4 + 1],
                    (float)zs[i * 4 + 2], (float)zs[i * 4 + 3]};
        faccA[i] = zi;                         // fold z into A-part acc init
    }

#pragma unroll
    for (int c = 0; c < 8; c++) {
        f16x8 af = *(const f16x8*)&hb[m * 264 + c * 32 + q * 8];
#pragma unroll
        for (int i = 0; i < 2; i++) {
            faccD[i] = __builtin_amdgcn_mfma_f32_16x16x32_f16(af, wd[c][i], faccD[i], 0, 0, 0);
            faccA[i] = __builtin_amdgcn_mfma_f32_16x16x32_f16(af, wa[c][i], faccA[i], 0, 0, 0);
        }
    }

#pragma unroll
    for (int i = 0; i < 2; i++) {
        int n = w * 32 + i * 16 + m;
#pragma unroll
        for (int r = 0; r < 4; r++) {
            int row = q * 4 + r;
            float xin = faccA[i][r];           // h@A + z
            // tanh(x) = 1 - 2/(exp(2x)+1), exp via native exp2, div via rcp.
            float e = __builtin_amdgcn_exp2f(xin * 2.8853900817779268f);
            float th = 1.0f - 2.0f * __builtin_amdgcn_rcpf(e + 1.0f);
            hm[i * 4 + r] += faccD[i][r] + (EPS * 0.0625f) * th;  // faccD=(EPS/16)(h@Dm)
            hn[row * 264 + n] = (_Float16)hm[i * 4 + r];          // h' = h/16
        }
    }
    __syncthreads();
}

__global__ __launch_bounds__(512, 2) void recur(const _Float16* __restrict__ Wsw,
                                                const _Float16* __restrict__ zp,
                                                const float* __restrict__ Dw,
                                                const float* __restrict__ Db,
                                                float* __restrict__ out) {
    __shared__ __align__(16) _Float16 hbuf0[16 * 264];
    __shared__ __align__(16) _Float16 hbuf1[16 * 264];
    __shared__ float Yep[16 * 257];
    int tid = threadIdx.x;
    int l = tid & 63, w = tid >> 6, m = l & 15, q = l >> 4;
    int wg = blockIdx.x;

    // resident weight fragments: 32 f16x8 = 128 regs (compiler places in AGPRs)
    f16x8 wd[8][2], wa[8][2];
    const f16x8* Wp = (const f16x8*)Wsw;
#pragma unroll
    for (int c = 0; c < 8; c++)
#pragma unroll
        for (int i = 0; i < 2; i++) {
            wd[c][i] = Wp[(((w * 2 + 0) * 8 + c) * 2 + i) * 64 + l];
            wa[c][i] = Wp[(((w * 2 + 1) * 8 + c) * 2 + i) * 64 + l];
        }
    // Pin: make values opaque so the compiler cannot rematerialize the
    // global loads inside the step loop.
#pragma unroll
    for (int c = 0; c < 8; c++)
#pragma unroll
        for (int i = 0; i < 2; i++)
            asm volatile("" : "+v"(wd[c][i]), "+v"(wa[c][i]));

    float hm[8];
#pragma unroll
    for (int e = 0; e < 8; e++) hm[e] = 0.0f;
    for (int idx = tid; idx < 16 * 264; idx += 512) hbuf0[idx] = (_Float16)0.0f;

    int zrow = wg * 16 + q * 4;               // this thread's h-row base
    int colb = w * 32 + m;                    // this thread's h-col base
    _Float16 zA[2][8], zB[2][8];
    load_zchunk(zA, zp, 0, zrow, colb);
    load_zchunk(zB, zp, 2, zrow, colb);
    __syncthreads();

    for (int t = 0; t < TT; t += 4) {
        step_fn(hbuf0, hbuf1, wd, wa, hm, zA[0], m, q, w);
        step_fn(hbuf1, hbuf0, wd, wa, hm, zA[1], m, q, w);
        load_zchunk(zA, zp, t + 4, zrow, colb);   // drains at next step barrier
        step_fn(hbuf0, hbuf1, wd, wa, hm, zB[0], m, q, w);
        step_fn(hbuf1, hbuf0, wd, wa, hm, zB[1], m, q, w);
        load_zchunk(zB, zp, t + 6, zrow, colb);
    }

    // epilogue: out[b][c] = h[b][:] @ Dw[c][:] + Db[c]   (h = 16*hm')
#pragma unroll
    for (int i = 0; i < 2; i++)
#pragma unroll
        for (int r = 0; r < 4; r++)
            Yep[(q * 4 + r) * 257 + w * 32 + i * 16 + m] = 16.0f * hm[i * 4 + r];
    __syncthreads();
    if (tid < 160) {
        int rr = tid / 10, c = tid - rr * 10;
        float s = Db[c];
        for (int k = 0; k < 256; k++) s += Yep[rr * 257 + k] * Dw[c * 256 + k];
        out[(wg * 16 + rr) * 10 + c] = s;
    }
}

// ---------------------------------------------------------------------------
extern "C" void kernel_launch(void* const* d_in, const int* in_sizes, int n_in,
                              void* d_out, int out_size, void* d_ws, size_t ws_size,
                              hipStream_t stream) {
    const float* x  = (const float*)d_in[0];
    const float* Ew = (const float*)d_in[1];
    const float* Eb = (const float*)d_in[2];
    const float* C  = (const float*)d_in[3];
    const float* B  = (const float*)d_in[4];
    const float* Dw = (const float*)d_in[5];
    const float* Db = (const float*)d_in[6];
    float* out = (float*)d_out;

    char* ws = (char*)d_ws;
    _Float16* zp  = (_Float16*)(ws);
    _Float16* Wsw = (_Float16*)(ws + WSW_OFF);
    _Float16* Esw = (_Float16*)(ws + ESW_OFF);

    hipLaunchKernelGGL(prep_w, dim3(64), dim3(256), 0, stream, C, B, Wsw);
    hipLaunchKernelGGL(prep_e, dim3(12), dim3(256), 0, stream, Ew, Esw);
    hipLaunchKernelGGL(zproj, dim3(4096), dim3(256), 0, stream, x, Eb, Esw, zp);
    hipLaunchKernelGGL(recur, dim3(16), dim3(512), 0, stream, Wsw, zp, Dw, Db, out);
}

// Round 7
// 1078.551 us; speedup vs baseline: 1.6308x; 1.0042x over previous
//
#include <hip/hip_runtime.h>

// Problem constants
#define BATCH 256
#define TT 1024
#define IN_DIM 96
#define NU 256
#define NC 10
#define EPS 0.01f
#define BETA 0.5f
#define GAMMA 0.0f

typedef _Float16 f16x8 __attribute__((ext_vector_type(8)));
typedef _Float16 f16x4 __attribute__((ext_vector_type(4)));
typedef float f32x4 __attribute__((ext_vector_type(4)));

// workspace layout (bytes)
// z: [t 1024][bb 16][n 256][bl 16] f16  (bb = batch/16 block = recur wg)
#define ZP_BYTES ((size_t)TT * 16 * 256 * 16 * 2)       // 134,217,728
#define WSW_OFF  ZP_BYTES
#define WSW_BYTES ((size_t)16384 * 16)                  // 262,144
#define ESW_OFF  (WSW_OFF + WSW_BYTES)

// ---------------------------------------------------------------------------
// prep_w (v6, unchanged): Wd = EPS*Dm, Wa = 16*A as B-operand frags.
// Flat: [w 8][mat 2][c 8][i 2][lane 64][8 halfs]
__global__ void prep_w(const float* __restrict__ C, const float* __restrict__ B,
                       _Float16* __restrict__ Wsw) {
    int u = blockIdx.x * 256 + threadIdx.x;   // 16384 units
    int l = u & 63;
    int i = (u >> 6) & 1;
    int c = (u >> 7) & 7;
    int mat = (u >> 10) & 1;
    int w = u >> 11;                          // 0..7
    int n = w * 32 + i * 16 + (l & 15);
    int kb = c * 32 + (l >> 4) * 8;
    const float* M = mat ? C : B;             // mat0: Dm from B; mat1: A from C
    float scale = mat ? 16.0f : EPS;
    f16x8 v;
#pragma unroll
    for (int j = 0; j < 8; j++) {
        int k = kb + j;
        float m1 = M[k * NU + n];
        float m2 = M[n * NU + k];
        float val = BETA * (m1 - m2) + (1.0f - BETA) * (m1 + m2)
                    - ((k == n) ? GAMMA : 0.0f);
        v[j] = (_Float16)(val * scale);
    }
    ((f16x8*)Wsw)[u] = v;
}

// ---------------------------------------------------------------------------
// prep_e (unchanged): E_w -> B-frags for z = x @ E_w^T (K=96, N=256).
// Flat: [w 4][c 3][i 4][lane 64][8 halfs]
__global__ void prep_e(const float* __restrict__ Ew, _Float16* __restrict__ Esw) {
    int u = blockIdx.x * 256 + threadIdx.x;   // 3072 units
    int l = u & 63;
    int i = (u >> 6) & 3;
    int wc = u >> 8;
    int c = wc % 3;
    int w = wc / 3;
    int n = w * 64 + i * 16 + (l & 15);
    int kb = c * 32 + (l >> 4) * 8;
    f16x8 v;
#pragma unroll
    for (int j = 0; j < 8; j++)
        v[j] = (_Float16)Ew[n * IN_DIM + kb + j];
    ((f16x8*)Esw)[u] = v;
}

// ---------------------------------------------------------------------------
// zproj v7: block = (bb 16-batch) x (tb: 16 timesteps). 256 thr = 4 waves,
// wave wz owns n-cols [wz*64, wz*64+64). A-frags loaded directly from global
// (coalesced 128B per m-row). Output transposed via padded LDS tile into
// z[t][bb][n][bl] with contiguous 32B/thread stores (2KB/wave).
__global__ __launch_bounds__(256) void zproj(const float* __restrict__ x,
                                             const float* __restrict__ Eb,
                                             const _Float16* __restrict__ Esw,
                                             _Float16* __restrict__ zp) {
    __shared__ __align__(16) _Float16 zt[2][256 * 24];  // [n][16 + pad8]
    int tid = threadIdx.x;
    int l = tid & 63, wz = tid >> 6, m = l & 15, q = l >> 4;
    int bb = blockIdx.x & 15, tb = blockIdx.x >> 4;
    int t0 = tb * 16, B0 = bb * 16;

    f16x8 ef[3][4];
    const f16x8* Ep = (const f16x8*)Esw;
#pragma unroll
    for (int c = 0; c < 3; c++)
#pragma unroll
        for (int i = 0; i < 4; i++)
            ef[c][i] = Ep[((wz * 3 + c) * 4 + i) * 64 + l];
    float eb[4];
#pragma unroll
    for (int i = 0; i < 4; i++) eb[i] = Eb[wz * 64 + i * 16 + m];

    // A-frag source: x[b = B0+m][t][f = c*32 + q*8 + j]
    const float* xbase = x + (size_t)(B0 + m) * TT * IN_DIM + q * 8;

    for (int t = 0; t < 16; t++) {
        f16x8 af[3];
#pragma unroll
        for (int c = 0; c < 3; c++) {
            const float* px = xbase + (size_t)(t0 + t) * IN_DIM + c * 32;
            float4 v0 = *(const float4*)px;
            float4 v1 = *(const float4*)(px + 4);
            f16x8 a;
            a[0] = (_Float16)v0.x; a[1] = (_Float16)v0.y;
            a[2] = (_Float16)v0.z; a[3] = (_Float16)v0.w;
            a[4] = (_Float16)v1.x; a[5] = (_Float16)v1.y;
            a[6] = (_Float16)v1.z; a[7] = (_Float16)v1.w;
            af[c] = a;
        }
        f32x4 acc[4];
#pragma unroll
        for (int i = 0; i < 4; i++) { f32x4 e4 = {eb[i], eb[i], eb[i], eb[i]}; acc[i] = e4; }
#pragma unroll
        for (int c = 0; c < 3; c++)
#pragma unroll
            for (int i = 0; i < 4; i++)
                acc[i] = __builtin_amdgcn_mfma_f32_16x16x32_f16(af[c], ef[c][i], acc[i], 0, 0, 0);

        // C-frag: value(b-local = q*4+r, n = wz*64+i*16+m) -> zt[n*24 + q*4+r]
        _Float16* zb = zt[t & 1];
#pragma unroll
        for (int i = 0; i < 4; i++) {
            f16x4 o = {(_Float16)acc[i][0], (_Float16)acc[i][1],
                       (_Float16)acc[i][2], (_Float16)acc[i][3]};
            *(f16x4*)&zb[(wz * 64 + i * 16 + m) * 24 + q * 4] = o;
        }
        __syncthreads();
        // store: thread tid handles n = tid -> 32B contiguous
        {
            _Float16* src = &zb[tid * 24];
            f16x8 s0 = *(f16x8*)src;
            f16x8 s1 = *(f16x8*)(src + 8);
            _Float16* dst = zp + ((((size_t)(t0 + t) * 16) + bb) * 256 + tid) * 16;
            *(f16x8*)dst = s0;
            *(f16x8*)(dst + 8) = s1;
        }
        __syncthreads();
    }
}

// ---------------------------------------------------------------------------
// Recurrence v7: green v6 skeleton; z now 2x f16x4 (b64) loads per step from
// the recur-native layout (SGPR base + const VGPR offset), chunk-2 prefetch.

__device__ __forceinline__ void load_z2(f16x4 zc[2][2],
                                        const _Float16* __restrict__ zp,
                                        int tb, int wg, size_t voff0, size_t voff1) {
#pragma unroll
    for (int s = 0; s < 2; s++) {
        int ts = tb + s; ts = (ts > TT - 1) ? TT - 1 : ts;
        const _Float16* pz = zp + ((size_t)ts * 16 + wg) * 4096;
        zc[s][0] = *(const f16x4*)(pz + voff0);
        zc[s][1] = *(const f16x4*)(pz + voff1);
    }
}

__device__ __forceinline__ void step_fn(const _Float16* __restrict__ hb,
                                        _Float16* __restrict__ hn,
                                        const f16x8 wd[8][2], const f16x8 wa[8][2],
                                        float hm[8], const f16x4 zs[2],
                                        int m, int q, int w) {
    f32x4 faccD[2], faccA[2];
    f32x4 zero4 = {0.f, 0.f, 0.f, 0.f};
#pragma unroll
    for (int i = 0; i < 2; i++) {
        faccD[i] = zero4;
        f32x4 zi = {(float)zs[i][0], (float)zs[i][1],
                    (float)zs[i][2], (float)zs[i][3]};
        faccA[i] = zi;                         // fold z into A-part acc init
    }

#pragma unroll
    for (int c = 0; c < 8; c++) {
        f16x8 af = *(const f16x8*)&hb[m * 264 + c * 32 + q * 8];
#pragma unroll
        for (int i = 0; i < 2; i++) {
            faccD[i] = __builtin_amdgcn_mfma_f32_16x16x32_f16(af, wd[c][i], faccD[i], 0, 0, 0);
            faccA[i] = __builtin_amdgcn_mfma_f32_16x16x32_f16(af, wa[c][i], faccA[i], 0, 0, 0);
        }
    }

#pragma unroll
    for (int i = 0; i < 2; i++) {
        int n = w * 32 + i * 16 + m;
#pragma unroll
        for (int r = 0; r < 4; r++) {
            int row = q * 4 + r;
            float xin = faccA[i][r];           // h@A + z
            float e = __builtin_amdgcn_exp2f(xin * 2.8853900817779268f);
            float R = __builtin_amdgcn_rcpf(e + 1.0f);
            float s = hm[i * 4 + r] + faccD[i][r];
            hm[i * 4 + r] = s + (EPS * 0.0625f) - (2.0f * EPS * 0.0625f) * R;
            hn[row * 264 + n] = (_Float16)hm[i * 4 + r];   // h' = h/16
        }
    }
    __syncthreads();
}

__global__ __launch_bounds__(512, 2) void recur(const _Float16* __restrict__ Wsw,
                                                const _Float16* __restrict__ zp,
                                                const float* __restrict__ Dw,
                                                const float* __restrict__ Db,
                                                float* __restrict__ out) {
    __shared__ __align__(16) _Float16 hbuf0[16 * 264];
    __shared__ __align__(16) _Float16 hbuf1[16 * 264];
    __shared__ float Yep[16 * 257];
    int tid = threadIdx.x;
    int l = tid & 63, w = tid >> 6, m = l & 15, q = l >> 4;
    int wg = blockIdx.x;

    // resident weight fragments: 32 f16x8 = 128 regs (AGPR-placed)
    f16x8 wd[8][2], wa[8][2];
    const f16x8* Wp = (const f16x8*)Wsw;
#pragma unroll
    for (int c = 0; c < 8; c++)
#pragma unroll
        for (int i = 0; i < 2; i++) {
            wd[c][i] = Wp[(((w * 2 + 0) * 8 + c) * 2 + i) * 64 + l];
            wa[c][i] = Wp[(((w * 2 + 1) * 8 + c) * 2 + i) * 64 + l];
        }
#pragma unroll
    for (int c = 0; c < 8; c++)
#pragma unroll
        for (int i = 0; i < 2; i++)
            asm volatile("" : "+v"(wd[c][i]), "+v"(wa[c][i]));

    float hm[8];
#pragma unroll
    for (int e = 0; e < 8; e++) hm[e] = 0.0f;
    for (int idx = tid; idx < 16 * 264; idx += 512) hbuf0[idx] = (_Float16)0.0f;

    // z element offsets within a (t, wg) slab: (n*16 + q*4), n = w*32+m (+16)
    size_t voff0 = (size_t)(w * 32 + m) * 16 + q * 4;
    size_t voff1 = voff0 + 256;               // n + 16
    f16x4 zA[2][2], zB[2][2];
    load_z2(zA, zp, 0, wg, voff0, voff1);
    load_z2(zB, zp, 2, wg, voff0, voff1);
    __syncthreads();

    for (int t = 0; t < TT; t += 4) {
        step_fn(hbuf0, hbuf1, wd, wa, hm, zA[0], m, q, w);
        step_fn(hbuf1, hbuf0, wd, wa, hm, zA[1], m, q, w);
        load_z2(zA, zp, t + 4, wg, voff0, voff1);   // drains at next barrier
        step_fn(hbuf0, hbuf1, wd, wa, hm, zB[0], m, q, w);
        step_fn(hbuf1, hbuf0, wd, wa, hm, zB[1], m, q, w);
        load_z2(zB, zp, t + 6, wg, voff0, voff1);
    }

    // epilogue: out[b][c] = h[b][:] @ Dw[c][:] + Db[c]   (h = 16*hm')
#pragma unroll
    for (int i = 0; i < 2; i++)
#pragma unroll
        for (int r = 0; r < 4; r++)
            Yep[(q * 4 + r) * 257 + w * 32 + i * 16 + m] = 16.0f * hm[i * 4 + r];
    __syncthreads();
    if (tid < 160) {
        int rr = tid / 10, c = tid - rr * 10;
        float s = Db[c];
        for (int k = 0; k < 256; k++) s += Yep[rr * 257 + k] * Dw[c * 256 + k];
        out[(wg * 16 + rr) * 10 + c] = s;
    }
}

// ---------------------------------------------------------------------------
extern "C" void kernel_launch(void* const* d_in, const int* in_sizes, int n_in,
                              void* d_out, int out_size, void* d_ws, size_t ws_size,
                              hipStream_t stream) {
    const float* x  = (const float*)d_in[0];
    const float* Ew = (const float*)d_in[1];
    const float* Eb = (const float*)d_in[2];
    const float* C  = (const float*)d_in[3];
    const float* B  = (const float*)d_in[4];
    const float* Dw = (const float*)d_in[5];
    const float* Db = (const float*)d_in[6];
    float* out = (float*)d_out;

    char* ws = (char*)d_ws;
    _Float16* zp  = (_Float16*)(ws);
    _Float16* Wsw = (_Float16*)(ws + WSW_OFF);
    _Float16* Esw = (_Float16*)(ws + ESW_OFF);

    hipLaunchKernelGGL(prep_w, dim3(64), dim3(256), 0, stream, C, B, Wsw);
    hipLaunchKernelGGL(prep_e, dim3(12), dim3(256), 0, stream, Ew, Esw);
    hipLaunchKernelGGL(zproj, dim3(1024), dim3(256), 0, stream, x, Eb, Esw, zp);
    hipLaunchKernelGGL(recur, dim3(16), dim3(512), 0, stream, Wsw, zp, Dw, Db, out);
}